// Round 1
// baseline (764.971 us; speedup 1.0000x reference)
//
#include <hip/hip_runtime.h>
#include <hip/hip_bf16.h>

typedef __hip_bfloat16 bf16;
typedef __attribute__((ext_vector_type(8))) short bf16x8;   // 8 bf16 = 4 VGPRs (MFMA A/B frag)
typedef __attribute__((ext_vector_type(4))) float f32x4;    // MFMA C/D frag

#define ASYNC_CP16(gsrc, ldst)                                                              \
  __builtin_amdgcn_global_load_lds(                                                         \
      (const __attribute__((address_space(1))) unsigned int*)(gsrc),                        \
      (__attribute__((address_space(3))) unsigned int*)(ldst), 16, 0, 0)

#define BB 32
#define NN 1024
#define FF 512
#define HH 2048
#define M_ROWS (BB * NN)  // 32768

// ---------------------------------------------------------------- weight cast
__global__ __launch_bounds__(256) void cvt_f32_bf16(const float* __restrict__ s,
                                                    bf16* __restrict__ d, int n) {
  int i = blockIdx.x * 256 + threadIdx.x;
  if (i < n) d[i] = __float2bfloat16(s[i]);
}

// ---------------------------------------------------------------- stable argsort per row
// key = (order-preserving-u32(value) << 32) | index  -> ascending u64 sort == stable argsort.
// Outputs: xs_bits[row][j] = bf16(x[row][inv[j]])  (the MLP input, permuted)
//          inv_out[row][j] = inv permutation (rank of element j)
__global__ __launch_bounds__(256) void sort_rows(const float* __restrict__ x,
                                                 unsigned short* __restrict__ xs_bits,
                                                 unsigned short* __restrict__ inv_out) {
  __shared__ unsigned long long keys[FF];
  __shared__ float xrow[FF];
  __shared__ __align__(8) unsigned short invs[FF];
  __shared__ __align__(8) unsigned short xsb[FF];
  const int t = threadIdx.x;
  const int row = blockIdx.x;
  const float* xr = x + (size_t)row * FF;

  for (int i = t; i < FF; i += 256) {
    float v = xr[i];
    xrow[i] = v;
    unsigned u = __float_as_uint(v);
    unsigned s = u ^ ((unsigned)((int)u >> 31) | 0x80000000u);  // monotone map fp32->u32
    keys[i] = ((unsigned long long)s << 32) | (unsigned)i;
  }
  __syncthreads();

  for (int k = 2; k <= FF; k <<= 1) {
    for (int j = k >> 1; j > 0; j >>= 1) {
      for (int i = t; i < FF; i += 256) {
        int ixj = i ^ j;
        if (ixj > i) {
          unsigned long long a = keys[i], b = keys[ixj];
          bool up = ((i & k) == 0);
          if ((a > b) == up) { keys[i] = b; keys[ixj] = a; }
        }
      }
      __syncthreads();
    }
  }

  // sorted position i holds original index srt[i]; inv[srt[i]] = i; xs[srt[i]] = x[i]
  for (int i = t; i < FF; i += 256) {
    int j = (int)(unsigned)keys[i];  // low 32 bits = original index
    invs[j] = (unsigned short)i;
    __hip_bfloat16 hb = __float2bfloat16(xrow[i]);
    xsb[j] = *reinterpret_cast<unsigned short*>(&hb);
  }
  __syncthreads();

  // packed coalesced stores (2 x u16 per u32 per thread)
  ((unsigned*)xs_bits)[(size_t)row * 256 + t] = ((const unsigned*)xsb)[t];
  ((unsigned*)inv_out)[(size_t)row * 256 + t] = ((const unsigned*)invs)[t];
}

// ---------------------------------------------------------------- GEMM1: h = relu(xs @ W1^T + b1)
// A [M x 512] bf16 row-major, Bw [2048 x 512] bf16 row-major (B^T layout), C [M x 2048] bf16
__global__ __launch_bounds__(256) void gemm1_relu(const bf16* __restrict__ A,
                                                  const bf16* __restrict__ Bw,
                                                  const float* __restrict__ bias,
                                                  bf16* __restrict__ C) {
  constexpr int K = FF;   // 512
  constexpr int N = HH;   // 2048
  __shared__ __align__(16) bf16 As[128 * 32];
  __shared__ __align__(16) bf16 Bs[128 * 32];
  const int t = threadIdx.x;
  const int lane = t & 63, wave = t >> 6;
  const int waveM = wave >> 1, waveN = wave & 1;  // 2x2 waves, 64x64 each
  const int srow = lane >> 2;                     // staging: row within 16-row chunk
  const int scol = (lane & 3) * 8;                // staging: element col (16B)
  const size_t mBase = (size_t)blockIdx.x * 128;
  const size_t nBase = (size_t)blockIdx.y * 128;
  const int q0 = wave * 2, q1 = q0 + 1;
  const bf16* Ag0 = A + (mBase + q0 * 16 + srow) * K + scol;
  const bf16* Ag1 = A + (mBase + q1 * 16 + srow) * K + scol;
  const bf16* Bg0 = Bw + (nBase + q0 * 16 + srow) * K + scol;
  const bf16* Bg1 = Bw + (nBase + q1 * 16 + srow) * K + scol;
  bf16* Al0 = &As[q0 * 512];
  bf16* Al1 = &As[q1 * 512];
  bf16* Bl0 = &Bs[q0 * 512];
  bf16* Bl1 = &Bs[q1 * 512];
  const int fr = lane & 15;
  const int fk = (lane >> 4) * 8;

  f32x4 acc[4][4];
  f32x4 zero = {0.f, 0.f, 0.f, 0.f};
#pragma unroll
  for (int i = 0; i < 4; i++)
#pragma unroll
    for (int j = 0; j < 4; j++) acc[i][j] = zero;

  for (int k0 = 0; k0 < K; k0 += 32) {
    ASYNC_CP16(Ag0 + k0, Al0);
    ASYNC_CP16(Ag1 + k0, Al1);
    ASYNC_CP16(Bg0 + k0, Bl0);
    ASYNC_CP16(Bg1 + k0, Bl1);
    __syncthreads();
    bf16x8 af[4], bfr[4];
#pragma unroll
    for (int mt = 0; mt < 4; mt++)
      af[mt] = *(const bf16x8*)&As[(waveM * 64 + mt * 16 + fr) * 32 + fk];
#pragma unroll
    for (int nt = 0; nt < 4; nt++)
      bfr[nt] = *(const bf16x8*)&Bs[(waveN * 64 + nt * 16 + fr) * 32 + fk];
#pragma unroll
    for (int mt = 0; mt < 4; mt++)
#pragma unroll
      for (int nt = 0; nt < 4; nt++)
        acc[mt][nt] = __builtin_amdgcn_mfma_f32_16x16x32_bf16(af[mt], bfr[nt], acc[mt][nt], 0, 0, 0);
    __syncthreads();
  }

  // epilogue: bias + relu, store bf16. C/D layout: col = lane&15, row = (lane>>4)*4 + reg
  const int cn = lane & 15;
  const int cm = (lane >> 4) * 4;
  float b4[4];
#pragma unroll
  for (int nt = 0; nt < 4; nt++) b4[nt] = bias[nBase + waveN * 64 + nt * 16 + cn];
#pragma unroll
  for (int mt = 0; mt < 4; mt++) {
#pragma unroll
    for (int nt = 0; nt < 4; nt++) {
      size_t gn = nBase + waveN * 64 + nt * 16 + cn;
#pragma unroll
      for (int r = 0; r < 4; r++) {
        size_t gm = mBase + waveM * 64 + mt * 16 + cm + r;
        float v = acc[mt][nt][r] + b4[nt];
        v = fmaxf(v, 0.f);
        C[gm * N + gn] = __float2bfloat16(v);
      }
    }
  }
}

// ---------------------------------------------------------------- GEMM2: z = h @ W2^T + b2; out[inv[j]] = z[j] + xs[j]
__global__ __launch_bounds__(256) void gemm2_scatter(const bf16* __restrict__ A,   // h [M x 2048]
                                                     const bf16* __restrict__ Bw,  // W2 [512 x 2048]
                                                     const float* __restrict__ bias,
                                                     const unsigned short* __restrict__ xs_bits,
                                                     const unsigned short* __restrict__ inv16,
                                                     float* __restrict__ out) {
  constexpr int K = HH;  // 2048
  __shared__ __align__(16) bf16 As[128 * 32];
  __shared__ __align__(16) bf16 Bs[128 * 32];
  const int t = threadIdx.x;
  const int lane = t & 63, wave = t >> 6;
  const int waveM = wave >> 1, waveN = wave & 1;
  const int srow = lane >> 2;
  const int scol = (lane & 3) * 8;
  const size_t mBase = (size_t)blockIdx.x * 128;
  const size_t nBase = (size_t)blockIdx.y * 128;
  const int q0 = wave * 2, q1 = q0 + 1;
  const bf16* Ag0 = A + (mBase + q0 * 16 + srow) * K + scol;
  const bf16* Ag1 = A + (mBase + q1 * 16 + srow) * K + scol;
  const bf16* Bg0 = Bw + (nBase + q0 * 16 + srow) * K + scol;
  const bf16* Bg1 = Bw + (nBase + q1 * 16 + srow) * K + scol;
  bf16* Al0 = &As[q0 * 512];
  bf16* Al1 = &As[q1 * 512];
  bf16* Bl0 = &Bs[q0 * 512];
  bf16* Bl1 = &Bs[q1 * 512];
  const int fr = lane & 15;
  const int fk = (lane >> 4) * 8;

  f32x4 acc[4][4];
  f32x4 zero = {0.f, 0.f, 0.f, 0.f};
#pragma unroll
  for (int i = 0; i < 4; i++)
#pragma unroll
    for (int j = 0; j < 4; j++) acc[i][j] = zero;

  for (int k0 = 0; k0 < K; k0 += 32) {
    ASYNC_CP16(Ag0 + k0, Al0);
    ASYNC_CP16(Ag1 + k0, Al1);
    ASYNC_CP16(Bg0 + k0, Bl0);
    ASYNC_CP16(Bg1 + k0, Bl1);
    __syncthreads();
    bf16x8 af[4], bfr[4];
#pragma unroll
    for (int mt = 0; mt < 4; mt++)
      af[mt] = *(const bf16x8*)&As[(waveM * 64 + mt * 16 + fr) * 32 + fk];
#pragma unroll
    for (int nt = 0; nt < 4; nt++)
      bfr[nt] = *(const bf16x8*)&Bs[(waveN * 64 + nt * 16 + fr) * 32 + fk];
#pragma unroll
    for (int mt = 0; mt < 4; mt++)
#pragma unroll
      for (int nt = 0; nt < 4; nt++)
        acc[mt][nt] = __builtin_amdgcn_mfma_f32_16x16x32_bf16(af[mt], bfr[nt], acc[mt][nt], 0, 0, 0);
    __syncthreads();
  }

  // epilogue: + b2 + xs (skip), scatter to out[row][inv[j]]
  const int cn = lane & 15;
  const int cm = (lane >> 4) * 4;
  float b4[4];
#pragma unroll
  for (int nt = 0; nt < 4; nt++) b4[nt] = bias[nBase + waveN * 64 + nt * 16 + cn];
#pragma unroll
  for (int mt = 0; mt < 4; mt++) {
#pragma unroll
    for (int r = 0; r < 4; r++) {
      size_t grow = mBase + waveM * 64 + mt * 16 + cm + r;
      const unsigned short* xsr = xs_bits + grow * FF;
      const unsigned short* invr = inv16 + grow * FF;
      float* outr = out + grow * FF;
#pragma unroll
      for (int nt = 0; nt < 4; nt++) {
        int j = (int)(nBase + waveN * 64 + nt * 16 + cn);
        float xv = __uint_as_float(((unsigned)xsr[j]) << 16);  // bf16 -> fp32 exact
        float v = acc[mt][nt][r] + b4[nt] + xv;
        outr[invr[j]] = v;
      }
    }
  }
}

// ---------------------------------------------------------------- launch
extern "C" void kernel_launch(void* const* d_in, const int* in_sizes, int n_in,
                              void* d_out, int out_size, void* d_ws, size_t ws_size,
                              hipStream_t stream) {
  const float* x  = (const float*)d_in[0];
  const float* W1 = (const float*)d_in[1];
  const float* b1 = (const float*)d_in[2];
  const float* W2 = (const float*)d_in[3];
  const float* b2 = (const float*)d_in[4];
  float* out = (float*)d_out;

  char* ws = (char*)d_ws;
  unsigned short* xs  = (unsigned short*)(ws);               // 32 MB bf16 bits
  unsigned short* inv = (unsigned short*)(ws + 33554432);    // 32 MB u16
  bf16* h   = (bf16*)(ws + 67108864);                        // 128 MB
  bf16* W1b = (bf16*)(ws + 201326592);                       // 2 MB
  bf16* W2b = (bf16*)(ws + 203423744);                       // 2 MB

  cvt_f32_bf16<<<(HH * FF + 255) / 256, 256, 0, stream>>>(W1, W1b, HH * FF);
  cvt_f32_bf16<<<(FF * HH + 255) / 256, 256, 0, stream>>>(W2, W2b, FF * HH);
  sort_rows<<<M_ROWS, 256, 0, stream>>>(x, xs, inv);
  gemm1_relu<<<dim3(M_ROWS / 128, HH / 128), 256, 0, stream>>>((const bf16*)xs, W1b, b1, h);
  gemm2_scatter<<<dim3(M_ROWS / 128, FF / 128), 256, 0, stream>>>(h, W2b, b2, xs, inv, out);
}

// Round 3
// 545.667 us; speedup vs baseline: 1.4019x; 1.4019x over previous
//
#include <hip/hip_runtime.h>
#include <hip/hip_bf16.h>

typedef __hip_bfloat16 bf16;
typedef __attribute__((ext_vector_type(8))) short bf16x8;   // 8 bf16 = 4 VGPRs (MFMA A/B frag)
typedef __attribute__((ext_vector_type(4))) float f32x4;    // MFMA C/D frag

#define ASYNC_CP16(gsrc, ldst)                                                              \
  __builtin_amdgcn_global_load_lds(                                                         \
      (const __attribute__((address_space(1))) unsigned int*)(gsrc),                        \
      (__attribute__((address_space(3))) unsigned int*)(ldst), 16, 0, 0)

#define BB 32
#define NN 1024
#define FF 512
#define HH 2048
#define M_ROWS (BB * NN)  // 32768

// ---------------------------------------------------------------- weight cast
__global__ __launch_bounds__(256) void cvt_f32_bf16(const float* __restrict__ s,
                                                    bf16* __restrict__ d, int n) {
  int i = blockIdx.x * 256 + threadIdx.x;
  if (i < n) d[i] = __float2bfloat16(s[i]);
}

// ---------------------------------------------------------------- stable argsort per row
// One row of 512 per WAVE; 8 u64 keys/lane in registers.
// key = mono_u32(val) << 32 | orig_idx   (unique keys, idx tie-break => stable argsort)
// Bitonic over virtual index v = lane*8 + r:
//   j >= 8 : cross-lane chunk exchange via shfl_xor(d = j/8)
//   j <  8 : in-register compare-exchange
// Scatter identity (j = srt[v] = low bits of sorted key at position v):
//   inv[j] = v
//   xs[j]  = x[inv[j]] = x[v]  — the lane's OWN original value vals[r] (v = lane*8+r),
//                                NOT the sorted element's value x[j].  (R2 bug was here.)
__global__ __launch_bounds__(256) void sort_rows_wave(const float* __restrict__ x,
                                                      unsigned* __restrict__ xs_pack,
                                                      unsigned* __restrict__ inv_pack) {
  __shared__ unsigned scat[4 * FF];  // 4 waves/block, 512 u32 per row
  const int t = threadIdx.x;
  const int lane = t & 63;
  const int w = t >> 6;
  const size_t row = (size_t)blockIdx.x * 4 + w;
  const float* xr = x + row * FF;

  float4 v0 = *(const float4*)(xr + lane * 8);
  float4 v1 = *(const float4*)(xr + lane * 8 + 4);
  float vals[8] = {v0.x, v0.y, v0.z, v0.w, v1.x, v1.y, v1.z, v1.w};

  unsigned long long key[8];
#pragma unroll
  for (int r = 0; r < 8; r++) {
    unsigned u = __float_as_uint(vals[r]);
    unsigned s = u ^ ((unsigned)((int)u >> 31) | 0x80000000u);  // monotone fp32->u32
    key[r] = ((unsigned long long)s << 32) | (unsigned)(lane * 8 + r);
  }

#pragma unroll
  for (int k = 2; k <= 512; k <<= 1) {
#pragma unroll
    for (int j = k >> 1; j > 0; j >>= 1) {
      if (j >= 8) {
        const int d = j >> 3;  // lane distance
#pragma unroll
        for (int r = 0; r < 8; r++) {
          unsigned long long o = __shfl_xor(key[r], d, 64);
          bool asc = (((lane * 8 + r) & k) == 0);
          bool lower = ((lane & d) == 0);
          bool keepmin = (asc == lower);
          bool minemin = key[r] < o;
          key[r] = (minemin == keepmin) ? key[r] : o;
        }
      } else {
#pragma unroll
        for (int r = 0; r < 8; r++) {
          if ((r & j) == 0) {
            const int a = r, b = r | j;
            bool asc = (((lane * 8 + a) & k) == 0);
            unsigned long long ka = key[a], kb = key[b];
            bool sw = ((ka > kb) == asc);
            key[a] = sw ? kb : ka;
            key[b] = sw ? ka : kb;
          }
        }
      }
    }
  }

  // scatter: sorted position v = lane*8+r holds original index j in low bits.
  // xs[j] = bf16(x[v]) = bf16(vals[r]);  inv[j] = v.
  const int base = w * FF;
#pragma unroll
  for (int r = 0; r < 8; r++) {
    unsigned j = (unsigned)key[r] & 0xFFFFu;
    __hip_bfloat16 hb = __float2bfloat16(vals[r]);
    unsigned hbits = *(unsigned short*)&hb;
    scat[base + j] = (hbits << 16) | (unsigned)(lane * 8 + r);
  }
  __syncthreads();

  // coalesced read-back + packed u16 stores (16B per lane per array)
  uint4 xo, io;
  unsigned p0, p1;
  const unsigned* sb = &scat[base + lane * 8];
  p0 = sb[0]; p1 = sb[1];
  xo.x = (p0 >> 16) | (p1 & 0xFFFF0000u);        io.x = (p0 & 0xFFFFu) | (p1 << 16);
  p0 = sb[2]; p1 = sb[3];
  xo.y = (p0 >> 16) | (p1 & 0xFFFF0000u);        io.y = (p0 & 0xFFFFu) | (p1 << 16);
  p0 = sb[4]; p1 = sb[5];
  xo.z = (p0 >> 16) | (p1 & 0xFFFF0000u);        io.z = (p0 & 0xFFFFu) | (p1 << 16);
  p0 = sb[6]; p1 = sb[7];
  xo.w = (p0 >> 16) | (p1 & 0xFFFF0000u);        io.w = (p0 & 0xFFFFu) | (p1 << 16);
  *(uint4*)(xs_pack + row * 256 + lane * 4) = xo;
  *(uint4*)(inv_pack + row * 256 + lane * 4) = io;
}

// ---------------------------------------------------------------- GEMM1: h = relu(xs @ W1^T + b1)
// A [M x 512] bf16 row-major, Bw [2048 x 512] bf16 row-major (B^T layout), C [M x 2048] bf16
__global__ __launch_bounds__(256) void gemm1_relu(const bf16* __restrict__ A,
                                                  const bf16* __restrict__ Bw,
                                                  const float* __restrict__ bias,
                                                  bf16* __restrict__ C) {
  constexpr int K = FF;   // 512
  constexpr int N = HH;   // 2048
  __shared__ __align__(16) bf16 As[128 * 32];
  __shared__ __align__(16) bf16 Bs[128 * 32];
  const int t = threadIdx.x;
  const int lane = t & 63, wave = t >> 6;
  const int waveM = wave >> 1, waveN = wave & 1;  // 2x2 waves, 64x64 each
  const int srow = lane >> 2;
  const int scol = (lane & 3) * 8;
  const size_t mBase = (size_t)blockIdx.x * 128;
  const size_t nBase = (size_t)blockIdx.y * 128;
  const int q0 = wave * 2, q1 = q0 + 1;
  const bf16* Ag0 = A + (mBase + q0 * 16 + srow) * K + scol;
  const bf16* Ag1 = A + (mBase + q1 * 16 + srow) * K + scol;
  const bf16* Bg0 = Bw + (nBase + q0 * 16 + srow) * K + scol;
  const bf16* Bg1 = Bw + (nBase + q1 * 16 + srow) * K + scol;
  bf16* Al0 = &As[q0 * 512];
  bf16* Al1 = &As[q1 * 512];
  bf16* Bl0 = &Bs[q0 * 512];
  bf16* Bl1 = &Bs[q1 * 512];
  const int fr = lane & 15;
  const int fk = (lane >> 4) * 8;

  f32x4 acc[4][4];
  f32x4 zero = {0.f, 0.f, 0.f, 0.f};
#pragma unroll
  for (int i = 0; i < 4; i++)
#pragma unroll
    for (int j = 0; j < 4; j++) acc[i][j] = zero;

  for (int k0 = 0; k0 < K; k0 += 32) {
    ASYNC_CP16(Ag0 + k0, Al0);
    ASYNC_CP16(Ag1 + k0, Al1);
    ASYNC_CP16(Bg0 + k0, Bl0);
    ASYNC_CP16(Bg1 + k0, Bl1);
    __syncthreads();
    bf16x8 af[4], bfr[4];
#pragma unroll
    for (int mt = 0; mt < 4; mt++)
      af[mt] = *(const bf16x8*)&As[(waveM * 64 + mt * 16 + fr) * 32 + fk];
#pragma unroll
    for (int nt = 0; nt < 4; nt++)
      bfr[nt] = *(const bf16x8*)&Bs[(waveN * 64 + nt * 16 + fr) * 32 + fk];
#pragma unroll
    for (int mt = 0; mt < 4; mt++)
#pragma unroll
      for (int nt = 0; nt < 4; nt++)
        acc[mt][nt] = __builtin_amdgcn_mfma_f32_16x16x32_bf16(af[mt], bfr[nt], acc[mt][nt], 0, 0, 0);
    __syncthreads();
  }

  const int cn = lane & 15;
  const int cm = (lane >> 4) * 4;
  float b4[4];
#pragma unroll
  for (int nt = 0; nt < 4; nt++) b4[nt] = bias[nBase + waveN * 64 + nt * 16 + cn];
#pragma unroll
  for (int mt = 0; mt < 4; mt++) {
#pragma unroll
    for (int nt = 0; nt < 4; nt++) {
      size_t gn = nBase + waveN * 64 + nt * 16 + cn;
#pragma unroll
      for (int r = 0; r < 4; r++) {
        size_t gm = mBase + waveM * 64 + mt * 16 + cm + r;
        float v = acc[mt][nt][r] + b4[nt];
        v = fmaxf(v, 0.f);
        C[gm * N + gn] = __float2bfloat16(v);
      }
    }
  }
}

// ---------------------------------------------------------------- GEMM2: z = h @ W2^T + b2; out[inv[j]] = z[j] + xs[j]
__global__ __launch_bounds__(256) void gemm2_scatter(const bf16* __restrict__ A,   // h [M x 2048]
                                                     const bf16* __restrict__ Bw,  // W2 [512 x 2048]
                                                     const float* __restrict__ bias,
                                                     const unsigned short* __restrict__ xs_bits,
                                                     const unsigned short* __restrict__ inv16,
                                                     float* __restrict__ out) {
  constexpr int K = HH;  // 2048
  __shared__ __align__(16) bf16 As[128 * 32];
  __shared__ __align__(16) bf16 Bs[128 * 32];
  const int t = threadIdx.x;
  const int lane = t & 63, wave = t >> 6;
  const int waveM = wave >> 1, waveN = wave & 1;
  const int srow = lane >> 2;
  const int scol = (lane & 3) * 8;
  const size_t mBase = (size_t)blockIdx.x * 128;
  const size_t nBase = (size_t)blockIdx.y * 128;
  const int q0 = wave * 2, q1 = q0 + 1;
  const bf16* Ag0 = A + (mBase + q0 * 16 + srow) * K + scol;
  const bf16* Ag1 = A + (mBase + q1 * 16 + srow) * K + scol;
  const bf16* Bg0 = Bw + (nBase + q0 * 16 + srow) * K + scol;
  const bf16* Bg1 = Bw + (nBase + q1 * 16 + srow) * K + scol;
  bf16* Al0 = &As[q0 * 512];
  bf16* Al1 = &As[q1 * 512];
  bf16* Bl0 = &Bs[q0 * 512];
  bf16* Bl1 = &Bs[q1 * 512];
  const int fr = lane & 15;
  const int fk = (lane >> 4) * 8;

  f32x4 acc[4][4];
  f32x4 zero = {0.f, 0.f, 0.f, 0.f};
#pragma unroll
  for (int i = 0; i < 4; i++)
#pragma unroll
    for (int j = 0; j < 4; j++) acc[i][j] = zero;

  for (int k0 = 0; k0 < K; k0 += 32) {
    ASYNC_CP16(Ag0 + k0, Al0);
    ASYNC_CP16(Ag1 + k0, Al1);
    ASYNC_CP16(Bg0 + k0, Bl0);
    ASYNC_CP16(Bg1 + k0, Bl1);
    __syncthreads();
    bf16x8 af[4], bfr[4];
#pragma unroll
    for (int mt = 0; mt < 4; mt++)
      af[mt] = *(const bf16x8*)&As[(waveM * 64 + mt * 16 + fr) * 32 + fk];
#pragma unroll
    for (int nt = 0; nt < 4; nt++)
      bfr[nt] = *(const bf16x8*)&Bs[(waveN * 64 + nt * 16 + fr) * 32 + fk];
#pragma unroll
    for (int mt = 0; mt < 4; mt++)
#pragma unroll
      for (int nt = 0; nt < 4; nt++)
        acc[mt][nt] = __builtin_amdgcn_mfma_f32_16x16x32_bf16(af[mt], bfr[nt], acc[mt][nt], 0, 0, 0);
    __syncthreads();
  }

  const int cn = lane & 15;
  const int cm = (lane >> 4) * 4;
  float b4[4];
#pragma unroll
  for (int nt = 0; nt < 4; nt++) b4[nt] = bias[nBase + waveN * 64 + nt * 16 + cn];
#pragma unroll
  for (int mt = 0; mt < 4; mt++) {
#pragma unroll
    for (int r = 0; r < 4; r++) {
      size_t grow = mBase + waveM * 64 + mt * 16 + cm + r;
      const unsigned short* xsr = xs_bits + grow * FF;
      const unsigned short* invr = inv16 + grow * FF;
      float* outr = out + grow * FF;
#pragma unroll
      for (int nt = 0; nt < 4; nt++) {
        int j = (int)(nBase + waveN * 64 + nt * 16 + cn);
        float xv = __uint_as_float(((unsigned)xsr[j]) << 16);  // bf16 -> fp32 exact
        float v = acc[mt][nt][r] + b4[nt] + xv;
        outr[invr[j]] = v;
      }
    }
  }
}

// ---------------------------------------------------------------- launch
extern "C" void kernel_launch(void* const* d_in, const int* in_sizes, int n_in,
                              void* d_out, int out_size, void* d_ws, size_t ws_size,
                              hipStream_t stream) {
  const float* x  = (const float*)d_in[0];
  const float* W1 = (const float*)d_in[1];
  const float* b1 = (const float*)d_in[2];
  const float* W2 = (const float*)d_in[3];
  const float* b2 = (const float*)d_in[4];
  float* out = (float*)d_out;

  char* ws = (char*)d_ws;
  unsigned short* xs  = (unsigned short*)(ws);               // 32 MB bf16 bits
  unsigned short* inv = (unsigned short*)(ws + 33554432);    // 32 MB u16
  bf16* h   = (bf16*)(ws + 67108864);                        // 128 MB
  bf16* W1b = (bf16*)(ws + 201326592);                       // 2 MB
  bf16* W2b = (bf16*)(ws + 203423744);                       // 2 MB

  cvt_f32_bf16<<<(HH * FF + 255) / 256, 256, 0, stream>>>(W1, W1b, HH * FF);
  cvt_f32_bf16<<<(FF * HH + 255) / 256, 256, 0, stream>>>(W2, W2b, FF * HH);
  sort_rows_wave<<<M_ROWS / 4, 256, 0, stream>>>(x, (unsigned*)xs, (unsigned*)inv);
  gemm1_relu<<<dim3(M_ROWS / 128, HH / 128), 256, 0, stream>>>((const bf16*)xs, W1b, b1, h);
  gemm2_scatter<<<dim3(M_ROWS / 128, FF / 128), 256, 0, stream>>>(h, W2b, b2, xs, inv, out);
}

// Round 4
// 414.139 us; speedup vs baseline: 1.8471x; 1.3176x over previous
//
#include <hip/hip_runtime.h>
#include <hip/hip_bf16.h>

typedef __hip_bfloat16 bf16;
typedef __attribute__((ext_vector_type(8))) short bf16x8;   // 8 bf16 = 4 VGPRs (MFMA A/B frag)
typedef __attribute__((ext_vector_type(4))) float f32x4;    // MFMA C/D frag

#define ASYNC_CP16(gsrc, ldst)                                                              \
  __builtin_amdgcn_global_load_lds(                                                         \
      (const __attribute__((address_space(1))) unsigned int*)(gsrc),                        \
      (__attribute__((address_space(3))) unsigned int*)(ldst), 16, 0, 0)

#define BB 32
#define NN 1024
#define FF 512
#define HH 2048
#define M_ROWS (BB * NN)  // 32768

// ---------------------------------------------------------------- weight cast
__global__ __launch_bounds__(256) void cvt_f32_bf16(const float* __restrict__ s,
                                                    bf16* __restrict__ d, int n) {
  int i = blockIdx.x * 256 + threadIdx.x;
  if (i < n) d[i] = __float2bfloat16(s[i]);
}

// ---------------------------------------------------------------- stable argsort per row
// One row of 512 per WAVE; 8 u64 keys/lane in registers.
// key = mono_u32(val) << 32 | orig_idx   (unique keys, idx tie-break => stable argsort)
// Outputs:
//   xs[row][j]  = bf16(x[row][inv[j]]) = scatter of lane value vals[r] to j=srt[v]
//   srt[row][v] = original index at sorted position v  (direct from keys, coalesced)
__global__ __launch_bounds__(256) void sort_rows_wave(const float* __restrict__ x,
                                                      unsigned* __restrict__ xs_pack,
                                                      unsigned* __restrict__ srt_pack) {
  __shared__ __align__(16) unsigned short scatx[4 * FF];  // 4 waves/block, 512 u16 per row
  const int t = threadIdx.x;
  const int lane = t & 63;
  const int w = t >> 6;
  const size_t row = (size_t)blockIdx.x * 4 + w;
  const float* xr = x + row * FF;

  float4 v0 = *(const float4*)(xr + lane * 8);
  float4 v1 = *(const float4*)(xr + lane * 8 + 4);
  float vals[8] = {v0.x, v0.y, v0.z, v0.w, v1.x, v1.y, v1.z, v1.w};

  unsigned long long key[8];
#pragma unroll
  for (int r = 0; r < 8; r++) {
    unsigned u = __float_as_uint(vals[r]);
    unsigned s = u ^ ((unsigned)((int)u >> 31) | 0x80000000u);  // monotone fp32->u32
    key[r] = ((unsigned long long)s << 32) | (unsigned)(lane * 8 + r);
  }

#pragma unroll
  for (int k = 2; k <= 512; k <<= 1) {
#pragma unroll
    for (int j = k >> 1; j > 0; j >>= 1) {
      if (j >= 8) {
        const int d = j >> 3;  // lane distance
#pragma unroll
        for (int r = 0; r < 8; r++) {
          unsigned long long o = __shfl_xor(key[r], d, 64);
          bool asc = (((lane * 8 + r) & k) == 0);
          bool lower = ((lane & d) == 0);
          bool keepmin = (asc == lower);
          bool minemin = key[r] < o;
          key[r] = (minemin == keepmin) ? key[r] : o;
        }
      } else {
#pragma unroll
        for (int r = 0; r < 8; r++) {
          if ((r & j) == 0) {
            const int a = r, b = r | j;
            bool asc = (((lane * 8 + a) & k) == 0);
            unsigned long long ka = key[a], kb = key[b];
            bool sw = ((ka > kb) == asc);
            key[a] = sw ? kb : ka;
            key[b] = sw ? ka : kb;
          }
        }
      }
    }
  }

  // xs scatter: sorted position v = lane*8+r holds original index j; xs[j] = bf16(vals[r]).
  const int base = w * FF;
  unsigned j8[8];
#pragma unroll
  for (int r = 0; r < 8; r++) {
    j8[r] = (unsigned)key[r] & 0xFFFFu;
    __hip_bfloat16 hb = __float2bfloat16(vals[r]);
    scatx[base + j8[r]] = *(unsigned short*)&hb;
  }

  // srt: direct coalesced pack (8 u16 -> uint4)
  uint4 so;
  so.x = j8[0] | (j8[1] << 16);
  so.y = j8[2] | (j8[3] << 16);
  so.z = j8[4] | (j8[5] << 16);
  so.w = j8[6] | (j8[7] << 16);
  *(uint4*)(srt_pack + row * 256 + lane * 4) = so;

  __syncthreads();
  uint4 xo = *(const uint4*)&scatx[base + lane * 8];
  *(uint4*)(xs_pack + row * 256 + lane * 4) = xo;
}

// ---------------------------------------------------------------- GEMM (m97-style, fat block)
// 512 threads = 8 waves (2 waveM x 4 waveN), block tile 128 x 256, BK=32.
// A [M x K] bf16 row-major; Bw [N x K] bf16 row-major (B^T input); C [M x N] bf16.
// Epilogue: C = (RELU ? relu : id)(A@B^T + bias), coalesced bf16 stores.
template <int RELU, int K, int N>
__global__ __launch_bounds__(512, 4) void gemm_fat(const bf16* __restrict__ A,
                                                   const bf16* __restrict__ Bw,
                                                   const float* __restrict__ bias,
                                                   bf16* __restrict__ C) {
  __shared__ __align__(16) bf16 As[128 * 32];  // 8 KB
  __shared__ __align__(16) bf16 Bs[256 * 32];  // 16 KB
  const int t = threadIdx.x;
  const int lane = t & 63, wave = t >> 6;          // 8 waves
  const int waveM = wave >> 2, waveN = wave & 3;   // 2 x 4 grid of 64x64 wave tiles
  const int srow = lane >> 2;                      // staging row within 16-row chunk
  const int scol = (lane & 3) * 8;                 // staging col (16B)
  const size_t mBase = (size_t)blockIdx.x * 128;
  const size_t nBase = (size_t)blockIdx.y * 256;
  // staging assignment: wave w loads A rows [16w,16w+16) and B rows [32w,32w+32)
  const bf16* Ag  = A  + (mBase + wave * 16 + srow) * (size_t)K + scol;
  const bf16* Bg0 = Bw + (nBase + wave * 32 + srow) * (size_t)K + scol;
  const bf16* Bg1 = Bw + (nBase + wave * 32 + 16 + srow) * (size_t)K + scol;
  bf16* Al  = &As[wave * 16 * 32];
  bf16* Bl0 = &Bs[wave * 32 * 32];
  bf16* Bl1 = &Bs[(wave * 32 + 16) * 32];
  const int fr = lane & 15;
  const int fk = (lane >> 4) * 8;

  f32x4 acc[4][4];
  f32x4 zero = {0.f, 0.f, 0.f, 0.f};
#pragma unroll
  for (int i = 0; i < 4; i++)
#pragma unroll
    for (int j = 0; j < 4; j++) acc[i][j] = zero;

  for (int k0 = 0; k0 < K; k0 += 32) {
    ASYNC_CP16(Ag + k0, Al);
    ASYNC_CP16(Bg0 + k0, Bl0);
    ASYNC_CP16(Bg1 + k0, Bl1);
    __syncthreads();
    bf16x8 af[4], bfr[4];
#pragma unroll
    for (int mt = 0; mt < 4; mt++)
      af[mt] = *(const bf16x8*)&As[(waveM * 64 + mt * 16 + fr) * 32 + fk];
#pragma unroll
    for (int nt = 0; nt < 4; nt++)
      bfr[nt] = *(const bf16x8*)&Bs[(waveN * 64 + nt * 16 + fr) * 32 + fk];
#pragma unroll
    for (int mt = 0; mt < 4; mt++)
#pragma unroll
      for (int nt = 0; nt < 4; nt++)
        acc[mt][nt] = __builtin_amdgcn_mfma_f32_16x16x32_bf16(af[mt], bfr[nt], acc[mt][nt], 0, 0, 0);
    __syncthreads();
  }

  // C/D layout: col = lane&15, row = (lane>>4)*4 + reg
  const int cn = lane & 15;
  const int cm = (lane >> 4) * 4;
  float b4[4];
#pragma unroll
  for (int nt = 0; nt < 4; nt++) b4[nt] = bias[nBase + waveN * 64 + nt * 16 + cn];
#pragma unroll
  for (int mt = 0; mt < 4; mt++) {
#pragma unroll
    for (int nt = 0; nt < 4; nt++) {
      size_t gn = nBase + waveN * 64 + nt * 16 + cn;
#pragma unroll
      for (int r = 0; r < 4; r++) {
        size_t gm = mBase + waveM * 64 + mt * 16 + cm + r;
        float v = acc[mt][nt][r] + b4[nt];
        if (RELU) v = fmaxf(v, 0.f);
        C[gm * N + gn] = __float2bfloat16(v);
      }
    }
  }
}

// ---------------------------------------------------------------- permute + skip
// out[row][i] = fp32(z[row][srt[i]]) + x[row][i]   (one row per wave, z row via LDS)
__global__ __launch_bounds__(256) void permute_add(const bf16* __restrict__ z,
                                                   const unsigned* __restrict__ srt_pack,
                                                   const float* __restrict__ x,
                                                   float* __restrict__ out) {
  __shared__ __align__(16) unsigned short zr[4][FF];
  const int t = threadIdx.x;
  const int lane = t & 63;
  const int w = t >> 6;
  const size_t row = (size_t)blockIdx.x * 4 + w;

  *(uint4*)&zr[w][lane * 8] = *(const uint4*)(z + row * FF + lane * 8);
  uint4 sv = *(const uint4*)(srt_pack + row * 256 + lane * 4);
  float4 x0 = *(const float4*)(x + row * FF + lane * 8);
  float4 x1 = *(const float4*)(x + row * FF + lane * 8 + 4);
  __syncthreads();

  unsigned idx[8] = {sv.x & 0xFFFFu, sv.x >> 16, sv.y & 0xFFFFu, sv.y >> 16,
                     sv.z & 0xFFFFu, sv.z >> 16, sv.w & 0xFFFFu, sv.w >> 16};
  float xv[8] = {x0.x, x0.y, x0.z, x0.w, x1.x, x1.y, x1.z, x1.w};
  float4 o0, o1;
  float* op = &o0.x;
#pragma unroll
  for (int r = 0; r < 8; r++) {
    float zf = __uint_as_float(((unsigned)zr[w][idx[r]]) << 16);
    ((r < 4) ? (&o0.x) : (&o1.x))[r & 3] = zf + xv[r];
  }
  (void)op;
  *(float4*)(out + row * FF + lane * 8) = o0;
  *(float4*)(out + row * FF + lane * 8 + 4) = o1;
}

// ---------------------------------------------------------------- launch
extern "C" void kernel_launch(void* const* d_in, const int* in_sizes, int n_in,
                              void* d_out, int out_size, void* d_ws, size_t ws_size,
                              hipStream_t stream) {
  const float* x  = (const float*)d_in[0];
  const float* W1 = (const float*)d_in[1];
  const float* b1 = (const float*)d_in[2];
  const float* W2 = (const float*)d_in[3];
  const float* b2 = (const float*)d_in[4];
  float* out = (float*)d_out;

  char* ws = (char*)d_ws;
  // xs dead after gemm1 -> z aliases xs region (both 32 MiB). Footprint 196 MiB.
  unsigned* xs  = (unsigned*)(ws);                           // 32 MiB bf16 bits (xs)
  bf16*     z   = (bf16*)(ws);                               // 32 MiB bf16 (aliases xs)
  unsigned* srt = (unsigned*)(ws + 33554432);                // 32 MiB u16 srt
  bf16* h   = (bf16*)(ws + 67108864);                        // 128 MiB
  bf16* W1b = (bf16*)(ws + 201326592);                       // 2 MiB
  bf16* W2b = (bf16*)(ws + 203423744);                       // 2 MiB

  cvt_f32_bf16<<<(HH * FF + 255) / 256, 256, 0, stream>>>(W1, W1b, HH * FF);
  cvt_f32_bf16<<<(FF * HH + 255) / 256, 256, 0, stream>>>(W2, W2b, FF * HH);
  sort_rows_wave<<<M_ROWS / 4, 256, 0, stream>>>(x, xs, srt);
  // h = relu(xs @ W1^T + b1): M=32768, K=512, N=2048
  gemm_fat<1, FF, HH><<<dim3(M_ROWS / 128, HH / 256), 512, 0, stream>>>((const bf16*)xs, W1b, b1, h);
  // z = h @ W2^T + b2: M=32768, K=2048, N=512
  gemm_fat<0, HH, FF><<<dim3(M_ROWS / 128, FF / 256), 512, 0, stream>>>(h, W2b, b2, z);
  permute_add<<<M_ROWS / 4, 256, 0, stream>>>(z, srt, x, out);
}

// Round 5
// 364.115 us; speedup vs baseline: 2.1009x; 1.1374x over previous
//
#include <hip/hip_runtime.h>
#include <hip/hip_bf16.h>

typedef __hip_bfloat16 bf16;
typedef __attribute__((ext_vector_type(8))) short bf16x8;   // 8 bf16 = 4 VGPRs (MFMA A/B frag)
typedef __attribute__((ext_vector_type(4))) float f32x4;    // MFMA C/D frag

#define ASYNC_CP16(gsrc, ldst)                                                              \
  __builtin_amdgcn_global_load_lds(                                                         \
      (const __attribute__((address_space(1))) unsigned int*)(gsrc),                        \
      (__attribute__((address_space(3))) unsigned int*)(ldst), 16, 0, 0)

#define BB 32
#define NN 1024
#define FF 512
#define HH 2048
#define M_ROWS (BB * NN)  // 32768

// ---------------------------------------------------------------- weight casts (fused)
__global__ __launch_bounds__(256) void cvt_pair(const float* __restrict__ a, bf16* __restrict__ da,
                                                const float* __restrict__ b, bf16* __restrict__ db,
                                                int n) {
  int i = blockIdx.x * 256 + threadIdx.x;
  if (i < n) {
    da[i] = __float2bfloat16(a[i]);
    db[i] = __float2bfloat16(b[i]);
  }
}

// ---------------------------------------------------------------- DPP xor-exchange (VALU pipe)
// update_dpp(old, src, ctrl, row_mask, bank_mask, bound_ctrl): full masks + in-row patterns
// => every lane valid. xor1 = quad_perm(1,0,3,2)=0xB1; xor2 = quad_perm(2,3,0,1)=0x4E;
// xor8 = row_ror:8 = 0x128 ((i±8)&15 == i^8).
template <int CTRL>
__device__ __forceinline__ unsigned long long dpp_xor64(unsigned long long k) {
  int lo = (int)(unsigned)k;
  int hi = (int)(unsigned)(k >> 32);
  int plo = __builtin_amdgcn_update_dpp(lo, lo, CTRL, 0xF, 0xF, false);
  int phi = __builtin_amdgcn_update_dpp(hi, hi, CTRL, 0xF, 0xF, false);
  return (((unsigned long long)(unsigned)phi) << 32) | (unsigned)plo;
}

// ---------------------------------------------------------------- stable argsort per row
// One row of 512 per WAVE; 8 u64 keys/lane in registers.
// key = mono_u32(val) << 32 | orig_idx   (unique keys, idx tie-break => stable argsort)
// Cross-lane levels (j>=8): DPP where d in {1,2,8}, ds_bpermute (shfl) for d in {4,16,32}.
// Outputs:
//   xs[row][j]  = bf16(x[row][inv[j]])  (scatter of lane value vals[r] to j=srt[v])
//   srt[row][v] = original index at sorted position v
__global__ __launch_bounds__(256) void sort_rows_wave(const float* __restrict__ x,
                                                      unsigned* __restrict__ xs_pack,
                                                      unsigned* __restrict__ srt_pack) {
  __shared__ __align__(16) unsigned short scatx[4 * FF];  // 4 waves/block, 512 u16 per row
  const int t = threadIdx.x;
  const int lane = t & 63;
  const int w = t >> 6;
  const size_t row = (size_t)blockIdx.x * 4 + w;
  const float* xr = x + row * FF;

  float4 v0 = *(const float4*)(xr + lane * 8);
  float4 v1 = *(const float4*)(xr + lane * 8 + 4);
  float vals[8] = {v0.x, v0.y, v0.z, v0.w, v1.x, v1.y, v1.z, v1.w};

  unsigned long long key[8];
#pragma unroll
  for (int r = 0; r < 8; r++) {
    unsigned u = __float_as_uint(vals[r]);
    unsigned s = u ^ ((unsigned)((int)u >> 31) | 0x80000000u);  // monotone fp32->u32
    key[r] = ((unsigned long long)s << 32) | (unsigned)(lane * 8 + r);
  }

#pragma unroll
  for (int k = 2; k <= 512; k <<= 1) {
#pragma unroll
    for (int j = k >> 1; j > 0; j >>= 1) {
      if (j >= 8) {
        const int d = j >> 3;  // lane distance
#pragma unroll
        for (int r = 0; r < 8; r++) {
          unsigned long long o;
          if (d == 1)       o = dpp_xor64<0xB1>(key[r]);
          else if (d == 2)  o = dpp_xor64<0x4E>(key[r]);
          else if (d == 8)  o = dpp_xor64<0x128>(key[r]);
          else              o = __shfl_xor(key[r], d, 64);
          bool asc = (((lane * 8 + r) & k) == 0);
          bool lower = ((lane & d) == 0);
          bool keepmin = (asc == lower);
          bool minemin = key[r] < o;
          key[r] = (minemin == keepmin) ? key[r] : o;
        }
      } else {
#pragma unroll
        for (int r = 0; r < 8; r++) {
          if ((r & j) == 0) {
            const int a = r, b = r | j;
            bool asc = (((lane * 8 + a) & k) == 0);
            unsigned long long ka = key[a], kb = key[b];
            bool sw = ((ka > kb) == asc);
            key[a] = sw ? kb : ka;
            key[b] = sw ? ka : kb;
          }
        }
      }
    }
  }

  // xs scatter: sorted position v = lane*8+r holds original index j; xs[j] = bf16(vals[r]).
  const int base = w * FF;
  unsigned j8[8];
#pragma unroll
  for (int r = 0; r < 8; r++) {
    j8[r] = (unsigned)key[r] & 0xFFFFu;
    __hip_bfloat16 hb = __float2bfloat16(vals[r]);
    scatx[base + j8[r]] = *(unsigned short*)&hb;
  }

  // srt: direct coalesced pack (8 u16 -> uint4)
  uint4 so;
  so.x = j8[0] | (j8[1] << 16);
  so.y = j8[2] | (j8[3] << 16);
  so.z = j8[4] | (j8[5] << 16);
  so.w = j8[6] | (j8[7] << 16);
  *(uint4*)(srt_pack + row * 256 + lane * 4) = so;

  __syncthreads();
  uint4 xo = *(const uint4*)&scatx[base + lane * 8];
  *(uint4*)(xs_pack + row * 256 + lane * 4) = xo;
}

// ---------------------------------------------------------------- GEMM (m97-style, fat block)
// 512 threads = 8 waves (2 waveM x 4 waveN), block tile 128 x 256, BK=32.
// A [M x K] bf16 row-major; Bw [N x K] bf16 row-major (B^T input); C [M x N] bf16.
// Epilogue: C = (RELU ? relu : id)(A@B^T + bias [+ xs_add]), coalesced bf16 stores.
// ADDX=1: xs_add has the same [M x N] layout as C. May ALIAS C: each element is
// read then written by the same thread (program order), and tiles are disjoint.
template <int RELU, int ADDX, int K, int N>
__global__ __launch_bounds__(512, 4) void gemm_fat(const bf16* __restrict__ A,
                                                   const bf16* __restrict__ Bw,
                                                   const float* __restrict__ bias,
                                                   const bf16* __restrict__ xs_add,
                                                   bf16* __restrict__ C) {
  __shared__ __align__(16) bf16 As[128 * 32];  // 8 KB
  __shared__ __align__(16) bf16 Bs[256 * 32];  // 16 KB
  const int t = threadIdx.x;
  const int lane = t & 63, wave = t >> 6;          // 8 waves
  const int waveM = wave >> 2, waveN = wave & 3;   // 2 x 4 grid of 64x64 wave tiles
  const int srow = lane >> 2;                      // staging row within 16-row chunk
  const int scol = (lane & 3) * 8;                 // staging col (16B)
  const size_t mBase = (size_t)blockIdx.x * 128;
  const size_t nBase = (size_t)blockIdx.y * 256;
  const bf16* Ag  = A  + (mBase + wave * 16 + srow) * (size_t)K + scol;
  const bf16* Bg0 = Bw + (nBase + wave * 32 + srow) * (size_t)K + scol;
  const bf16* Bg1 = Bw + (nBase + wave * 32 + 16 + srow) * (size_t)K + scol;
  bf16* Al  = &As[wave * 16 * 32];
  bf16* Bl0 = &Bs[wave * 32 * 32];
  bf16* Bl1 = &Bs[(wave * 32 + 16) * 32];
  const int fr = lane & 15;
  const int fk = (lane >> 4) * 8;

  f32x4 acc[4][4];
  f32x4 zero = {0.f, 0.f, 0.f, 0.f};
#pragma unroll
  for (int i = 0; i < 4; i++)
#pragma unroll
    for (int j = 0; j < 4; j++) acc[i][j] = zero;

  for (int k0 = 0; k0 < K; k0 += 32) {
    ASYNC_CP16(Ag + k0, Al);
    ASYNC_CP16(Bg0 + k0, Bl0);
    ASYNC_CP16(Bg1 + k0, Bl1);
    __syncthreads();
    bf16x8 af[4], bfr[4];
#pragma unroll
    for (int mt = 0; mt < 4; mt++)
      af[mt] = *(const bf16x8*)&As[(waveM * 64 + mt * 16 + fr) * 32 + fk];
#pragma unroll
    for (int nt = 0; nt < 4; nt++)
      bfr[nt] = *(const bf16x8*)&Bs[(waveN * 64 + nt * 16 + fr) * 32 + fk];
#pragma unroll
    for (int mt = 0; mt < 4; mt++)
#pragma unroll
      for (int nt = 0; nt < 4; nt++)
        acc[mt][nt] = __builtin_amdgcn_mfma_f32_16x16x32_bf16(af[mt], bfr[nt], acc[mt][nt], 0, 0, 0);
    __syncthreads();
  }

  // C/D layout: col = lane&15, row = (lane>>4)*4 + reg
  const int cn = lane & 15;
  const int cm = (lane >> 4) * 4;
  float b4[4];
#pragma unroll
  for (int nt = 0; nt < 4; nt++) b4[nt] = bias[nBase + waveN * 64 + nt * 16 + cn];
#pragma unroll
  for (int mt = 0; mt < 4; mt++) {
#pragma unroll
    for (int nt = 0; nt < 4; nt++) {
      size_t gn = nBase + waveN * 64 + nt * 16 + cn;
#pragma unroll
      for (int r = 0; r < 4; r++) {
        size_t gm = mBase + waveM * 64 + mt * 16 + cm + r;
        float v = acc[mt][nt][r] + b4[nt];
        if (RELU) v = fmaxf(v, 0.f);
        if (ADDX) v += __bfloat162float(xs_add[gm * N + gn]);
        C[gm * N + gn] = __float2bfloat16(v);
      }
    }
  }
}

// ---------------------------------------------------------------- final permute (pure gather)
// out[row][i] = fp32(zp[row][srt[i]])   where zp = z + xs (already summed in gemm2 epilogue)
__global__ __launch_bounds__(256) void permute_gather(const bf16* __restrict__ zp,
                                                      const unsigned* __restrict__ srt_pack,
                                                      float* __restrict__ out) {
  __shared__ __align__(16) unsigned short zr[4][FF];
  const int t = threadIdx.x;
  const int lane = t & 63;
  const int w = t >> 6;
  const size_t row = (size_t)blockIdx.x * 4 + w;

  *(uint4*)&zr[w][lane * 8] = *(const uint4*)(zp + row * FF + lane * 8);
  uint4 sv = *(const uint4*)(srt_pack + row * 256 + lane * 4);
  __syncthreads();

  unsigned idx[8] = {sv.x & 0xFFFFu, sv.x >> 16, sv.y & 0xFFFFu, sv.y >> 16,
                     sv.z & 0xFFFFu, sv.z >> 16, sv.w & 0xFFFFu, sv.w >> 16};
  float4 o0, o1;
#pragma unroll
  for (int r = 0; r < 8; r++) {
    float zf = __uint_as_float(((unsigned)zr[w][idx[r]]) << 16);
    ((r < 4) ? (&o0.x) : (&o1.x))[r & 3] = zf;
  }
  *(float4*)(out + row * FF + lane * 8) = o0;
  *(float4*)(out + row * FF + lane * 8 + 4) = o1;
}

// ---------------------------------------------------------------- launch
extern "C" void kernel_launch(void* const* d_in, const int* in_sizes, int n_in,
                              void* d_out, int out_size, void* d_ws, size_t ws_size,
                              hipStream_t stream) {
  const float* x  = (const float*)d_in[0];
  const float* W1 = (const float*)d_in[1];
  const float* b1 = (const float*)d_in[2];
  const float* W2 = (const float*)d_in[3];
  const float* b2 = (const float*)d_in[4];
  float* out = (float*)d_out;

  char* ws = (char*)d_ws;
  // z aliases xs ([M][512] bf16, identical layout): gemm2 reads xs(gm,gn) then writes
  // z(gm,gn) from the SAME thread, tiles disjoint across blocks -> safe. 196 MiB total.
  unsigned* xs  = (unsigned*)(ws);                           // 32 MiB bf16 xs
  bf16*     xsb = (bf16*)(ws);
  bf16*     z   = (bf16*)(ws);                               // aliases xs
  unsigned* srt = (unsigned*)(ws + 33554432);                // 32 MiB u16 srt
  bf16* h   = (bf16*)(ws + 67108864);                        // 128 MiB
  bf16* W1b = (bf16*)(ws + 201326592);                       // 2 MiB
  bf16* W2b = (bf16*)(ws + 203423744);                       // 2 MiB

  cvt_pair<<<(HH * FF + 255) / 256, 256, 0, stream>>>(W1, W1b, W2, W2b, HH * FF);
  sort_rows_wave<<<M_ROWS / 4, 256, 0, stream>>>(x, xs, srt);
  // h = relu(xs @ W1^T + b1): M=32768, K=512, N=2048
  gemm_fat<1, 0, FF, HH><<<dim3(M_ROWS / 128, HH / 256), 512, 0, stream>>>(xsb, W1b, b1, nullptr, h);
  // z = h @ W2^T + b2 + xs: M=32768, K=2048, N=512  (skip fused, sorted domain)
  gemm_fat<0, 1, HH, FF><<<dim3(M_ROWS / 128, FF / 256), 512, 0, stream>>>(h, W2b, b2, xsb, z);
  permute_gather<<<M_ROWS / 4, 256, 0, stream>>>(z, srt, out);
}